// Round 6
// baseline (602.340 us; speedup 1.0000x reference)
//
#include <hip/hip_runtime.h>
#include <cstdint>

// RGPR-GNN (GPR-GNN + RGCN basis-decomp convs) for MI355X.
// R17: R14 structure restored (lin2-epilogue fusion of R16 REVERTED: it
// regressed 496.5 -> 517.5; final_kernel is back) + agg reparallelized.
//  - agg v3: one WAVE per (dst,rel) SEGMENT (350K waves) instead of one wave
//    per dst. Avg segment = 1.7 edges -> the old per-dst kernel serialized a
//    12-edge chain + 7 shfl-heavy flush episodes per wave (VALUBusy 60%).
//    Now: 2 uniform drs loads + ~1.7 uniform esrc loads (SCALAR loads, no
//    ds_bpermute) + coalesced row loads + mean + one 256B write. Same traffic
//    (64.5MB random fetch + 87.5MB stream write), 7x wave concurrency.
//  - prep: cast_w1 + build_wcat2 merged (prep_weights). place de-atomic'd.
// Per layer:
//   agg_seg:   wave per (dst,rel), register accum, scalar edge loads.
//   gemm_layer: c=[curA|agg](K=1024)@Wcat2+bias, (relu if l<2), write bf16.
// Edge sort by (dst,rel) runs ONCE: hist(+rank) -> 3-kernel scan -> placement.

constexpr int N_NODES  = 50000;
constexpr int E_EDGES  = 600000;
constexpr int R_REL    = 7;
constexpr int HID      = 128;
constexpr int IN_C     = 256;
constexpr int L_LAYERS = 3;
constexpr int AGG_COLS = 896;           // 7*128 aggregated message columns
constexpr int K_CAT    = 1024;          // 128 self + 896 agg
constexpr int NR       = N_NODES * R_REL;            // 350000 segments
constexpr int SCANR_BLOCKS = (NR + 255) / 256;       // 1368
constexpr int WCAT_ELEMS = L_LAYERS * 128 * K_CAT;   // 393216

#define DEVI __device__ __forceinline__

using short8  = __attribute__((ext_vector_type(8))) short;
using floatx4 = __attribute__((ext_vector_type(4))) float;

DEVI unsigned short f2bf(float f) {
  unsigned u = __float_as_uint(f);
  unsigned r = (u + 0x7FFFu + ((u >> 16) & 1u)) >> 16;  // RNE
  return (unsigned short)r;
}
DEVI float bf2f(unsigned short h) { return __uint_as_float(((unsigned)h) << 16); }

// ---------------------------------------------------------------- weight prep
// t < WCAT_ELEMS: wcat2T[L][f=128][k=1024]; else w1T [128][256].
__global__ __launch_bounds__(256) void prep_weights(
    const float* __restrict__ w1,
    const float* __restrict__ comps,   // [L,R,8]
    const float* __restrict__ bases,   // [L,8,128,128]
    const float* __restrict__ roots,   // [L,128,128]
    unsigned short* __restrict__ w1T,
    unsigned short* __restrict__ wcat2T)
{
  int t = blockIdx.x * 256 + threadIdx.x;
  if (t < WCAT_ELEMS) {
    int l   = t >> 17;
    int rem = t & 131071;
    int f   = rem >> 10;
    int k   = rem & 1023;
    float v;
    if (k < 128) {
      v = roots[((size_t)l * 128 + k) * 128 + f];
    } else {
      int r = (k - 128) >> 7, d = (k - 128) & 127;
      const float* cp = comps + ((size_t)l * R_REL + r) * 8;
      const float* bp = bases + (((size_t)l * 8) * 128 + d) * 128 + f;
      float s = 0.f;
#pragma unroll
      for (int b = 0; b < 8; ++b) s += cp[b] * bp[(size_t)b * 128 * 128];
      v = s;
    }
    wcat2T[t] = f2bf(v);
  } else {
    int u = t - WCAT_ELEMS;
    if (u < HID * IN_C) {
      int m = u >> 8, k = u & 255;
      w1T[m * IN_C + k] = f2bf(w1[k * HID + m]);
    }
  }
}

// ------------------------------------------------- histogram (dst,rel) + rank
__global__ __launch_bounds__(256) void hist_kernel(
    const int* __restrict__ ei, const int* __restrict__ et,
    int* __restrict__ cntRel, int* __restrict__ erank)
{
  int e = blockIdx.x * 256 + threadIdx.x;
  if (e >= E_EDGES) return;
  int seg = ei[E_EDGES + e] * R_REL + et[e];
  erank[e] = atomicAdd(&cntRel[seg], 1);
}

// ---------------------------------------------------------------- scan over NR
__global__ __launch_bounds__(256) void scanA_kernel(
    const int* __restrict__ cnt, int* __restrict__ tmpOff,
    int* __restrict__ blockSums)
{
  __shared__ int s[256];
  int i = blockIdx.x * 256 + threadIdx.x;
  int v = (i < NR) ? cnt[i] : 0;
  s[threadIdx.x] = v;
  __syncthreads();
#pragma unroll
  for (int d = 1; d < 256; d <<= 1) {
    int t = (threadIdx.x >= d) ? s[threadIdx.x - d] : 0;
    __syncthreads();
    s[threadIdx.x] += t;
    __syncthreads();
  }
  if (i < NR) tmpOff[i] = s[threadIdx.x] - v;   // exclusive within block
  if (threadIdx.x == 255) blockSums[blockIdx.x] = s[255];
}

// single block, serial chunks with carry (SCANR_BLOCKS = 1368)
__global__ __launch_bounds__(256) void scanB_kernel(int* __restrict__ bs)
{
  __shared__ int s[256];
  __shared__ int carry;
  if (threadIdx.x == 0) carry = 0;
  __syncthreads();
  for (int base = 0; base < SCANR_BLOCKS; base += 256) {
    int cOld = carry;
    int i = base + threadIdx.x;
    int v = (i < SCANR_BLOCKS) ? bs[i] : 0;
    s[threadIdx.x] = v;
    __syncthreads();
#pragma unroll
    for (int d = 1; d < 256; d <<= 1) {
      int t = (threadIdx.x >= d) ? s[threadIdx.x - d] : 0;
      __syncthreads();
      s[threadIdx.x] += t;
      __syncthreads();
    }
    if (i < SCANR_BLOCKS) bs[i] = s[threadIdx.x] - v + cOld;  // exclusive
    __syncthreads();
    if (threadIdx.x == 0) carry = cOld + s[255];
    __syncthreads();
  }
}

__global__ __launch_bounds__(256) void scanC_kernel(
    const int* __restrict__ tmpOff, const int* __restrict__ blockSums,
    int* __restrict__ drs)
{
  int i = blockIdx.x * 256 + threadIdx.x;
  if (i < NR) drs[i] = tmpOff[i] + blockSums[blockIdx.x];
  if (i == 0) drs[NR] = E_EDGES;
}

// ---------------------------------------------------------------- placement
// Pure scatter: pos = drs[seg] + erank[e]. No atomics.
__global__ __launch_bounds__(256) void place_kernel(
    const int* __restrict__ ei, const int* __restrict__ et,
    const int* __restrict__ drs, const int* __restrict__ erank,
    unsigned short* __restrict__ esrc)
{
  int e = blockIdx.x * 256 + threadIdx.x;
  if (e >= E_EDGES) return;
  int seg = ei[E_EDGES + e] * R_REL + et[e];
  int pos = drs[seg] + erank[e];
  esrc[pos] = (unsigned short)ei[e];   // src < 50000 < 65536
}

// ---------------------------------------------------------------- aggregation
// R17: one WAVE per (dst,rel) segment. Bounds and edge srcs are wave-uniform
// -> scalar loads (no shuffles). 64 lanes x 2 dims cover the 256B row, fully
// coalesced. Empty segment -> writes zeros (sc=0). Same traffic as before,
// 7x the wave-level concurrency, ~no VALU walk machinery.
__global__ __launch_bounds__(256) void agg_seg_kernel(
    const unsigned short* __restrict__ curA,   // [N,128] bf16
    const unsigned short* __restrict__ esrc,   // sorted by (dst,rel)
    const int* __restrict__ drs,               // [N*R+1] segment starts
    unsigned short* __restrict__ aggB)         // [N,896] bf16
{
  const int lane = threadIdx.x & 63;
  const int seg  = blockIdx.x * 4 + (threadIdx.x >> 6);
  if (seg >= NR) return;
  const int a = drs[seg];
  const int b = drs[seg + 1];

  const unsigned* colp = (const unsigned*)curA + lane;   // row stride 64 uints
  float sx = 0.f, sy = 0.f;
  for (int e = a; e < b; ++e) {
    int src = (int)esrc[e];                    // wave-uniform -> scalar load
    unsigned u = colp[(size_t)src * 64];
    sx += __uint_as_float(u << 16);            // lo bf16
    sy += __uint_as_float(u & 0xFFFF0000u);    // hi bf16
  }
  int c = b - a;
  float sc = (c > 0) ? 1.0f / (float)c : 0.f;
  unsigned pck = (unsigned)f2bf(sx * sc) | ((unsigned)f2bf(sy * sc) << 16);
  // seg = dst*7 + r ; aggB row = [dst][r*128 + 2*lane]
  int dst = seg / R_REL, r = seg - dst * R_REL;
  ((unsigned*)aggB)[(size_t)dst * (AGG_COLS / 2) + r * 64 + lane] = pck;
}

// ---------------------------------------------------------------- lin1 MFMA GEMM
// M=64 tile (grid 782), K=256 in 2 phases; x read fp32 + cast DURING staging.
// Output: b0 = bf16(t0*(x@w1+b1)) ONLY (no fp32 hidden).
__global__ __launch_bounds__(256) void gemm_lin1(
    const float* __restrict__ x,              // [N,256] fp32
    const unsigned short* __restrict__ BT,    // w1T [128,256] bf16
    const float* __restrict__ bias,
    const float* __restrict__ temp,
    unsigned short* __restrict__ b0out)       // [N,128] bf16
{
  __shared__ unsigned short Atile[64][136];    // 17.4 KB
  __shared__ unsigned short Btile[128][136];   // 34.8 KB
  const int tid  = threadIdx.x;
  const int row0 = blockIdx.x * 64;
  const int lane = tid & 63;
  const int wid  = tid >> 6;
  const int wrow = (wid & 1) * 32;
  const int wcol = (wid >> 1) * 64;
  const int l15  = lane & 15;
  const int quad = lane >> 4;

  floatx4 acc[2][4] = {};

  for (int k0 = 0; k0 < IN_C; k0 += 128) {
    // A: 64 rows x 128 k, cast fp32->bf16 in flight. 1024 chunks, 4/thread.
#pragma unroll
    for (int it = 0; it < 4; ++it) {
      int chunk = it * 256 + tid;
      int r = chunk >> 4, cc = (chunk & 15) << 3;
      int grow = row0 + r;
      uint4 va = make_uint4(0u, 0u, 0u, 0u);
      if (grow < N_NODES) {
        const float* xp = x + (size_t)grow * IN_C + k0 + cc;
        float4 f0 = *(const float4*)xp;
        float4 f1 = *(const float4*)(xp + 4);
        va.x = (unsigned)f2bf(f0.x) | ((unsigned)f2bf(f0.y) << 16);
        va.y = (unsigned)f2bf(f0.z) | ((unsigned)f2bf(f0.w) << 16);
        va.z = (unsigned)f2bf(f1.x) | ((unsigned)f2bf(f1.y) << 16);
        va.w = (unsigned)f2bf(f1.z) | ((unsigned)f2bf(f1.w) << 16);
      }
      *(uint4*)(&Atile[r][cc]) = va;
    }
    // B: 128 rows (out cols) x 128 k. 2048 chunks, 8/thread.
#pragma unroll
    for (int it = 0; it < 8; ++it) {
      int chunk = it * 256 + tid;
      int n = chunk >> 4, cc = (chunk & 15) << 3;
      *(uint4*)(&Btile[n][cc]) =
          *(const uint4*)(BT + (size_t)n * IN_C + k0 + cc);
    }
    __syncthreads();
#pragma unroll
    for (int ks = 0; ks < 4; ++ks) {
      int kc = ks * 32 + quad * 8;
      short8 af[2], bfr[4];
#pragma unroll
      for (int i = 0; i < 2; ++i)
        af[i] = *(const short8*)(&Atile[wrow + i * 16 + l15][kc]);
#pragma unroll
      for (int j = 0; j < 4; ++j)
        bfr[j] = *(const short8*)(&Btile[wcol + j * 16 + l15][kc]);
#pragma unroll
      for (int i = 0; i < 2; ++i)
#pragma unroll
        for (int j = 0; j < 4; ++j)
          acc[i][j] = __builtin_amdgcn_mfma_f32_16x16x32_bf16(
              af[i], bfr[j], acc[i][j], 0, 0, 0);
    }
    __syncthreads();
  }

  // epilogue: b0 = bf16(t0*(acc+bias)) via LDS transpose.
  float t0 = temp[0];
#pragma unroll
  for (int i = 0; i < 2; ++i) {
    int lrow0 = wrow + i * 16 + quad * 4;
#pragma unroll
    for (int j = 0; j < 4; ++j) {
      int gcol = wcol + j * 16 + l15;
      float bb = bias[gcol];
#pragma unroll
      for (int r = 0; r < 4; ++r)
        Atile[lrow0 + r][gcol] = f2bf(t0 * (acc[i][j][r] + bb));
    }
  }
  __syncthreads();
#pragma unroll
  for (int it = 0; it < 4; ++it) {
    int chunk = it * 256 + tid;
    int r = chunk >> 4, cc = (chunk & 15) << 3;
    int grow = row0 + r;
    if (grow < N_NODES)
      *(uint4*)(b0out + (size_t)grow * HID + cc) = *(const uint4*)(&Atile[r][cc]);
  }
}

// ---------------------------------------------------------------- layer MFMA GEMM
// M=64 tile (grid 782), 4 waves, each 32rows x 64cols (acc 2x4). LDS 52.2 KB.
// Epilogue writes ONLY bf16 c = (l<2?relu:id)(acc+bias). No hidden RMW.
__global__ __launch_bounds__(256) void gemm_layer(
    const unsigned short* __restrict__ curA,   // [N,128] bf16 (in, = b_l)
    const unsigned short* __restrict__ aggB,   // [N,896] bf16
    const unsigned short* __restrict__ BT,     // wcat2T [128][1024] bf16
    const float* __restrict__ bias,
    unsigned short* __restrict__ bout,         // [N,128] bf16 (out, = b_{l+1})
    int layer)
{
  __shared__ unsigned short Atile[64][136];    // 17.4 KB
  __shared__ unsigned short Btile[128][136];   // 34.8 KB
  const int tid  = threadIdx.x;
  const int row0 = blockIdx.x * 64;
  const int lane = tid & 63;
  const int wid  = tid >> 6;
  const int wrow = (wid & 1) * 32;
  const int wcol = (wid >> 1) * 64;
  const int l15  = lane & 15;
  const int quad = lane >> 4;

  floatx4 acc[2][4] = {};

  for (int p = 0; p < 8; ++p) {
    // B tile: 128 rows (out cols) x 128 k slice. 2048 chunks, 8/thread.
#pragma unroll
    for (int it = 0; it < 8; ++it) {
      int chunk = it * 256 + tid;
      int n = chunk >> 4, cc = (chunk & 15) << 3;
      *(uint4*)(&Btile[n][cc]) =
          *(const uint4*)(BT + (size_t)n * K_CAT + p * 128 + cc);
    }
    // A tile: 64 rows x 128 k. 1024 chunks, 4/thread.
#pragma unroll
    for (int it = 0; it < 4; ++it) {
      int chunk = it * 256 + tid;
      int r = chunk >> 4, cc = (chunk & 15) << 3;
      int grow = row0 + r;
      uint4 va = make_uint4(0u, 0u, 0u, 0u);
      if (grow < N_NODES) {
        if (p == 0)
          va = *(const uint4*)(curA + (size_t)grow * HID + cc);
        else
          va = *(const uint4*)(aggB + (size_t)grow * AGG_COLS +
                               (p - 1) * 128 + cc);
      }
      *(uint4*)(&Atile[r][cc]) = va;
    }
    __syncthreads();
#pragma unroll
    for (int ks = 0; ks < 4; ++ks) {
      int kc = ks * 32 + quad * 8;
      short8 af[2], bfr[4];
#pragma unroll
      for (int i = 0; i < 2; ++i)
        af[i] = *(const short8*)(&Atile[wrow + i * 16 + l15][kc]);
#pragma unroll
      for (int j = 0; j < 4; ++j)
        bfr[j] = *(const short8*)(&Btile[wcol + j * 16 + l15][kc]);
#pragma unroll
      for (int i = 0; i < 2; ++i)
#pragma unroll
        for (int j = 0; j < 4; ++j)
          acc[i][j] = __builtin_amdgcn_mfma_f32_16x16x32_bf16(
              af[i], bfr[j], acc[i][j], 0, 0, 0);
    }
    __syncthreads();
  }

  // epilogue: bout = bf16((l<2?relu:id)(acc+bias)) via LDS transpose.
  const bool isLast = (layer == L_LAYERS - 1);
#pragma unroll
  for (int i = 0; i < 2; ++i) {
    int lrow0 = wrow + i * 16 + quad * 4;
#pragma unroll
    for (int j = 0; j < 4; ++j) {
      int gcol = wcol + j * 16 + l15;
      float bb = bias[gcol];
#pragma unroll
      for (int r = 0; r < 4; ++r) {
        float c = acc[i][j][r] + bb;
        if (!isLast) c = fmaxf(c, 0.f);
        Atile[lrow0 + r][gcol] = f2bf(c);
      }
    }
  }
  __syncthreads();
#pragma unroll
  for (int it = 0; it < 4; ++it) {
    int chunk = it * 256 + tid;
    int r = chunk >> 4, cc = (chunk & 15) << 3;
    int grow = row0 + r;
    if (grow < N_NODES)
      *(uint4*)(bout + (size_t)grow * HID + cc) = *(const uint4*)(&Atile[r][cc]);
  }
}

// ---------------------------------------------------------------- final linear
// h[d] = b0 + temp[1]*b1 + temp[2]*b2 + temp[3]*b3 (bf16 terms), then lin2.
__global__ __launch_bounds__(256) void final_kernel(
    const unsigned short* __restrict__ b0, const unsigned short* __restrict__ b1,
    const unsigned short* __restrict__ b2v, const unsigned short* __restrict__ b3,
    const float* __restrict__ temp,
    const float* __restrict__ w2, const float* __restrict__ b2bias,
    float* __restrict__ out)
{
  int node = blockIdx.x * 4 + (threadIdx.x >> 6);
  int lane = threadIdx.x & 63;
  if (node >= N_NODES) return;
  float t1 = temp[1], t2 = temp[2], t3 = temp[3];
  size_t base = (size_t)node * 64 + lane;      // uint index: dims 2*lane,2*lane+1
  unsigned u0 = ((const unsigned*)b0)[base];
  unsigned u1 = ((const unsigned*)b1)[base];
  unsigned u2 = ((const unsigned*)b2v)[base];
  unsigned u3 = ((const unsigned*)b3)[base];
  float hx = bf2f((unsigned short)(u0 & 0xFFFF)) +
             t1 * bf2f((unsigned short)(u1 & 0xFFFF)) +
             t2 * bf2f((unsigned short)(u2 & 0xFFFF)) +
             t3 * bf2f((unsigned short)(u3 & 0xFFFF));
  float hy = bf2f((unsigned short)(u0 >> 16)) +
             t1 * bf2f((unsigned short)(u1 >> 16)) +
             t2 * bf2f((unsigned short)(u2 >> 16)) +
             t3 * bf2f((unsigned short)(u3 >> 16));
  int d0 = lane * 2, d1 = lane * 2 + 1;
  float a0 = hx * w2[d0 * 2 + 0] + hy * w2[d1 * 2 + 0];
  float a1 = hx * w2[d0 * 2 + 1] + hy * w2[d1 * 2 + 1];
#pragma unroll
  for (int off = 32; off > 0; off >>= 1) {
    a0 += __shfl_down(a0, off);
    a1 += __shfl_down(a1, off);
  }
  if (lane == 0) {
    out[node * 2 + 0] = a0 + b2bias[0];
    out[node * 2 + 1] = a1 + b2bias[1];
  }
}

// ---------------------------------------------------------------- launcher
extern "C" void kernel_launch(void* const* d_in, const int* in_sizes, int n_in,
                              void* d_out, int out_size, void* d_ws, size_t ws_size,
                              hipStream_t stream) {
  const float* x     = (const float*)d_in[0];
  const int*   ei    = (const int*)d_in[1];
  const int*   et    = (const int*)d_in[2];
  const float* temp  = (const float*)d_in[3];
  const float* w1    = (const float*)d_in[4];
  const float* b1    = (const float*)d_in[5];
  const float* w2    = (const float*)d_in[6];
  const float* b2    = (const float*)d_in[7];
  const float* comps = (const float*)d_in[8];
  const float* bases = (const float*)d_in[9];
  const float* roots = (const float*)d_in[10];
  const float* cbias = (const float*)d_in[11];

  char* ws = (char*)d_ws;
  size_t off = 0;
  auto take = [&](size_t bytes) {
    char* p = ws + off;
    off = (off + bytes + 255) & ~(size_t)255;
    return p;
  };
  unsigned short* wcat2T = (unsigned short*)take((size_t)WCAT_ELEMS * 2);  // 0.8 MB
  unsigned short* w1T    = (unsigned short*)take((size_t)HID * IN_C * 2);  // 64 KB
  int*   cntRel  = (int*)take((size_t)NR * 4);                  // 1.4 MB
  int*   tmpOffR = (int*)take((size_t)NR * 4);                  // 1.4 MB
  int*   blockSumsR = (int*)take((size_t)SCANR_BLOCKS * 4);
  int*   drs     = (int*)take((size_t)(NR + 1) * 4);            // 1.4 MB
  int*   erank   = (int*)take((size_t)E_EDGES * 4);             // 2.4 MB
  unsigned short* esrc = (unsigned short*)take((size_t)E_EDGES * 2); // 1.2 MB
  unsigned short* bl[L_LAYERS + 1];
  for (int i = 0; i <= L_LAYERS; ++i)
    bl[i] = (unsigned short*)take((size_t)N_NODES * HID * 2);   // 4 x 12.8 MB
  unsigned short* aggB = (unsigned short*)take((size_t)N_NODES * AGG_COLS * 2); // 89.6 MB

  hipMemsetAsync(cntRel, 0, (size_t)NR * 4, stream);

  hipLaunchKernelGGL(prep_weights,
                     dim3((WCAT_ELEMS + HID * IN_C + 255) / 256), dim3(256),
                     0, stream, w1, comps, bases, roots, w1T, wcat2T);
  hipLaunchKernelGGL(hist_kernel, dim3((E_EDGES + 255) / 256), dim3(256), 0,
                     stream, ei, et, cntRel, erank);
  hipLaunchKernelGGL(scanA_kernel, dim3(SCANR_BLOCKS), dim3(256), 0, stream,
                     cntRel, tmpOffR, blockSumsR);
  hipLaunchKernelGGL(scanB_kernel, dim3(1), dim3(256), 0, stream, blockSumsR);
  hipLaunchKernelGGL(scanC_kernel, dim3(SCANR_BLOCKS), dim3(256), 0, stream,
                     tmpOffR, blockSumsR, drs);
  hipLaunchKernelGGL(place_kernel, dim3((E_EDGES + 255) / 256), dim3(256), 0,
                     stream, ei, et, drs, erank, esrc);

  const int rowBlocks64 = (N_NODES + 63) / 64;     // 782
  hipLaunchKernelGGL(gemm_lin1, dim3(rowBlocks64), dim3(256), 0, stream,
                     x, w1T, b1, temp, bl[0]);

  for (int l = 0; l < L_LAYERS; ++l) {
    hipLaunchKernelGGL(agg_seg_kernel, dim3((NR + 3) / 4), dim3(256),
                       0, stream, bl[l], esrc, drs, aggB);
    hipLaunchKernelGGL(gemm_layer, dim3(rowBlocks64), dim3(256), 0, stream,
                       bl[l], aggB, wcat2T + (size_t)l * 128 * K_CAT,
                       cbias + (size_t)l * HID, bl[l + 1], l);
  }

  hipLaunchKernelGGL(final_kernel, dim3((N_NODES + 3) / 4), dim3(256), 0, stream,
                     bl[0], bl[1], bl[2], bl[3], temp, w2, b2, (float*)d_out);
}

// Round 7
// 478.642 us; speedup vs baseline: 1.2584x; 1.2584x over previous
//
#include <hip/hip_runtime.h>
#include <cstdint>

// RGPR-GNN (GPR-GNN + RGCN basis-decomp convs) for MI355X.
// R18: agg_seg REVERTED (R17: 95us vs 61 — serial chain, no prefetch; agg_reg
// is the 3x-probed floor). gemm_layer rewritten:
//  - M=128 tile (grid 391), A fragments loaded DIRECT from global (aggB rows
//    have zero reuse; 16B/lane contiguous, 64B per quad — no LDS round-trip,
//    no A-stage barrier). LDS holds only B panel (34.8 KB), reused as the
//    epilogue transpose buffer. B L2 restage traffic halved vs M=64.
//  - unrolled ks-loop -> 16 independent A-loads hoisted per phase (pipelines
//    under B LDS reads + MFMA).
// Everything else = R14 (best verified 496.5us): agg_reg per-dst prefetch-16,
// de-atomic place, prep_weights merged, final_kernel separate.
// Per layer:
//   agg_reg:   one wave per dst, (dst,rel)-sorted edges, register accum.
//   gemm_layer: c=[curA|agg](K=1024)@Wcat2+bias, (relu if l<2), write bf16.
// Edge sort by (dst,rel) runs ONCE: hist(+rank) -> 3-kernel scan -> placement.

constexpr int N_NODES  = 50000;
constexpr int E_EDGES  = 600000;
constexpr int R_REL    = 7;
constexpr int HID      = 128;
constexpr int IN_C     = 256;
constexpr int L_LAYERS = 3;
constexpr int AGG_COLS = 896;           // 7*128 aggregated message columns
constexpr int K_CAT    = 1024;          // 128 self + 896 agg
constexpr int NR       = N_NODES * R_REL;            // 350000 segments
constexpr int SCANR_BLOCKS = (NR + 255) / 256;       // 1368
constexpr int WCAT_ELEMS = L_LAYERS * 128 * K_CAT;   // 393216

#define DEVI __device__ __forceinline__

using short8  = __attribute__((ext_vector_type(8))) short;
using floatx4 = __attribute__((ext_vector_type(4))) float;

DEVI unsigned short f2bf(float f) {
  unsigned u = __float_as_uint(f);
  unsigned r = (u + 0x7FFFu + ((u >> 16) & 1u)) >> 16;  // RNE
  return (unsigned short)r;
}
DEVI float bf2f(unsigned short h) { return __uint_as_float(((unsigned)h) << 16); }

// ---------------------------------------------------------------- weight prep
// t < WCAT_ELEMS: wcat2T[L][f=128][k=1024]; else w1T [128][256].
__global__ __launch_bounds__(256) void prep_weights(
    const float* __restrict__ w1,
    const float* __restrict__ comps,   // [L,R,8]
    const float* __restrict__ bases,   // [L,8,128,128]
    const float* __restrict__ roots,   // [L,128,128]
    unsigned short* __restrict__ w1T,
    unsigned short* __restrict__ wcat2T)
{
  int t = blockIdx.x * 256 + threadIdx.x;
  if (t < WCAT_ELEMS) {
    int l   = t >> 17;
    int rem = t & 131071;
    int f   = rem >> 10;
    int k   = rem & 1023;
    float v;
    if (k < 128) {
      v = roots[((size_t)l * 128 + k) * 128 + f];
    } else {
      int r = (k - 128) >> 7, d = (k - 128) & 127;
      const float* cp = comps + ((size_t)l * R_REL + r) * 8;
      const float* bp = bases + (((size_t)l * 8) * 128 + d) * 128 + f;
      float s = 0.f;
#pragma unroll
      for (int b = 0; b < 8; ++b) s += cp[b] * bp[(size_t)b * 128 * 128];
      v = s;
    }
    wcat2T[t] = f2bf(v);
  } else {
    int u = t - WCAT_ELEMS;
    if (u < HID * IN_C) {
      int m = u >> 8, k = u & 255;
      w1T[m * IN_C + k] = f2bf(w1[k * HID + m]);
    }
  }
}

// ------------------------------------------------- histogram (dst,rel) + rank
__global__ __launch_bounds__(256) void hist_kernel(
    const int* __restrict__ ei, const int* __restrict__ et,
    int* __restrict__ cntRel, int* __restrict__ erank)
{
  int e = blockIdx.x * 256 + threadIdx.x;
  if (e >= E_EDGES) return;
  int seg = ei[E_EDGES + e] * R_REL + et[e];
  erank[e] = atomicAdd(&cntRel[seg], 1);
}

// ---------------------------------------------------------------- scan over NR
__global__ __launch_bounds__(256) void scanA_kernel(
    const int* __restrict__ cnt, int* __restrict__ tmpOff,
    int* __restrict__ blockSums)
{
  __shared__ int s[256];
  int i = blockIdx.x * 256 + threadIdx.x;
  int v = (i < NR) ? cnt[i] : 0;
  s[threadIdx.x] = v;
  __syncthreads();
#pragma unroll
  for (int d = 1; d < 256; d <<= 1) {
    int t = (threadIdx.x >= d) ? s[threadIdx.x - d] : 0;
    __syncthreads();
    s[threadIdx.x] += t;
    __syncthreads();
  }
  if (i < NR) tmpOff[i] = s[threadIdx.x] - v;   // exclusive within block
  if (threadIdx.x == 255) blockSums[blockIdx.x] = s[255];
}

// single block, serial chunks with carry (SCANR_BLOCKS = 1368)
__global__ __launch_bounds__(256) void scanB_kernel(int* __restrict__ bs)
{
  __shared__ int s[256];
  __shared__ int carry;
  if (threadIdx.x == 0) carry = 0;
  __syncthreads();
  for (int base = 0; base < SCANR_BLOCKS; base += 256) {
    int cOld = carry;
    int i = base + threadIdx.x;
    int v = (i < SCANR_BLOCKS) ? bs[i] : 0;
    s[threadIdx.x] = v;
    __syncthreads();
#pragma unroll
    for (int d = 1; d < 256; d <<= 1) {
      int t = (threadIdx.x >= d) ? s[threadIdx.x - d] : 0;
      __syncthreads();
      s[threadIdx.x] += t;
      __syncthreads();
    }
    if (i < SCANR_BLOCKS) bs[i] = s[threadIdx.x] - v + cOld;  // exclusive
    __syncthreads();
    if (threadIdx.x == 0) carry = cOld + s[255];
    __syncthreads();
  }
}

__global__ __launch_bounds__(256) void scanC_kernel(
    const int* __restrict__ tmpOff, const int* __restrict__ blockSums,
    int* __restrict__ drs)
{
  int i = blockIdx.x * 256 + threadIdx.x;
  if (i < NR) drs[i] = tmpOff[i] + blockSums[blockIdx.x];
  if (i == 0) drs[NR] = E_EDGES;
}

// ---------------------------------------------------------------- placement
// Pure scatter: pos = drs[seg] + erank[e]. No atomics.
__global__ __launch_bounds__(256) void place_kernel(
    const int* __restrict__ ei, const int* __restrict__ et,
    const int* __restrict__ drs, const int* __restrict__ erank,
    unsigned short* __restrict__ esrc)
{
  int e = blockIdx.x * 256 + threadIdx.x;
  if (e >= E_EDGES) return;
  int seg = ei[E_EDGES + e] * R_REL + et[e];
  int pos = drs[seg] + erank[e];
  esrc[pos] = (unsigned short)ei[e];   // src < 50000 < 65536
}

// ---------------------------------------------------------------- aggregation
// One wave per dst; 64 lanes x 2 dims = full 256B curA row per edge (coalesced).
// Edges sorted (dst,rel). Batch-prefetch up to 16 independent row loads into
// statically-indexed registers, then segmented accumulate with a uniform
// relation-boundary walk (flush handles empty/coincident segments).
// 3x-probed floor: ~61us (MLP++: null; wave-per-seg: -55%; fusion: -160%).
constexpr int AGG_NPF = 16;
__global__ __launch_bounds__(256) void agg_reg_kernel(
    const unsigned short* __restrict__ curA,   // [N,128] bf16
    const unsigned short* __restrict__ esrc,   // sorted by (dst,rel)
    const int* __restrict__ drs,               // [N*R+1] segment starts
    unsigned short* __restrict__ aggB)         // [N,896] bf16
{
  const int tid  = threadIdx.x;
  const int lane = tid & 63;
  const int dst  = blockIdx.x * 4 + (tid >> 6);
  if (dst >= N_NODES) return;
  const int segBase = dst * R_REL;

  int bnd = drs[segBase + (lane & 7)];
  const int a0    = __shfl(bnd, 0);
  const int total = __shfl(bnd, 7) - a0;

  int pk = 0;
  if (lane < total) pk = (int)esrc[a0 + lane];   // covers total<=64 (deg avg 12)

  const unsigned* colp = (const unsigned*)curA + lane;   // row stride = 64 uints
  unsigned* outp = (unsigned*)(aggB + (size_t)dst * AGG_COLS) + lane;

  // uniform walk state (relative to a0)
  int r = 0;
  int segStart = 0;
  int segEnd = __shfl(bnd, 1) - a0;
  float sx = 0.f, sy = 0.f;
  int pos = 0;

#define AGG_FLUSH()                                                        \
  while (r < R_REL && segEnd == pos) {                                     \
    int c = segEnd - segStart;                                             \
    float sc = (c > 0) ? 1.0f / (float)c : 0.f;                            \
    unsigned pck = (unsigned)f2bf(sx * sc) | ((unsigned)f2bf(sy * sc) << 16); \
    outp[r * 64] = pck;                                                    \
    sx = 0.f; sy = 0.f;                                                    \
    segStart = segEnd;                                                     \
    ++r;                                                                   \
    segEnd = (r < R_REL) ? (__shfl(bnd, r + 1) - a0) : 0x7FFFFFFF;         \
  }

  AGG_FLUSH();

  for (int base = 0; base < total; base += AGG_NPF) {
    const int cnt = min(total - base, AGG_NPF);
    unsigned v[AGG_NPF];
#pragma unroll
    for (int e = 0; e < AGG_NPF; ++e) {
      if (e < cnt) {
        int idx = base + e;
        int src = (idx < 64) ? __shfl(pk, idx) : (int)esrc[a0 + idx];
        v[e] = colp[src * 64];
      }
    }
#pragma unroll
    for (int e = 0; e < AGG_NPF; ++e) {
      if (e >= cnt) break;
      unsigned u = v[e];
      sx += __uint_as_float(u << 16);            // lo bf16
      sy += __uint_as_float(u & 0xFFFF0000u);    // hi bf16
      ++pos;
      AGG_FLUSH();
    }
  }
#undef AGG_FLUSH
}

// ---------------------------------------------------------------- lin1 MFMA GEMM
// M=64 tile (grid 782), K=256 in 2 phases; x read fp32 + cast DURING staging.
// Output: b0 = bf16(t0*(x@w1+b1)) ONLY (no fp32 hidden).
__global__ __launch_bounds__(256) void gemm_lin1(
    const float* __restrict__ x,              // [N,256] fp32
    const unsigned short* __restrict__ BT,    // w1T [128,256] bf16
    const float* __restrict__ bias,
    const float* __restrict__ temp,
    unsigned short* __restrict__ b0out)       // [N,128] bf16
{
  __shared__ unsigned short Atile[64][136];    // 17.4 KB
  __shared__ unsigned short Btile[128][136];   // 34.8 KB
  const int tid  = threadIdx.x;
  const int row0 = blockIdx.x * 64;
  const int lane = tid & 63;
  const int wid  = tid >> 6;
  const int wrow = (wid & 1) * 32;
  const int wcol = (wid >> 1) * 64;
  const int l15  = lane & 15;
  const int quad = lane >> 4;

  floatx4 acc[2][4] = {};

  for (int k0 = 0; k0 < IN_C; k0 += 128) {
    // A: 64 rows x 128 k, cast fp32->bf16 in flight. 1024 chunks, 4/thread.
#pragma unroll
    for (int it = 0; it < 4; ++it) {
      int chunk = it * 256 + tid;
      int r = chunk >> 4, cc = (chunk & 15) << 3;
      int grow = row0 + r;
      uint4 va = make_uint4(0u, 0u, 0u, 0u);
      if (grow < N_NODES) {
        const float* xp = x + (size_t)grow * IN_C + k0 + cc;
        float4 f0 = *(const float4*)xp;
        float4 f1 = *(const float4*)(xp + 4);
        va.x = (unsigned)f2bf(f0.x) | ((unsigned)f2bf(f0.y) << 16);
        va.y = (unsigned)f2bf(f0.z) | ((unsigned)f2bf(f0.w) << 16);
        va.z = (unsigned)f2bf(f1.x) | ((unsigned)f2bf(f1.y) << 16);
        va.w = (unsigned)f2bf(f1.z) | ((unsigned)f2bf(f1.w) << 16);
      }
      *(uint4*)(&Atile[r][cc]) = va;
    }
    // B: 128 rows (out cols) x 128 k. 2048 chunks, 8/thread.
#pragma unroll
    for (int it = 0; it < 8; ++it) {
      int chunk = it * 256 + tid;
      int n = chunk >> 4, cc = (chunk & 15) << 3;
      *(uint4*)(&Btile[n][cc]) =
          *(const uint4*)(BT + (size_t)n * IN_C + k0 + cc);
    }
    __syncthreads();
#pragma unroll
    for (int ks = 0; ks < 4; ++ks) {
      int kc = ks * 32 + quad * 8;
      short8 af[2], bfr[4];
#pragma unroll
      for (int i = 0; i < 2; ++i)
        af[i] = *(const short8*)(&Atile[wrow + i * 16 + l15][kc]);
#pragma unroll
      for (int j = 0; j < 4; ++j)
        bfr[j] = *(const short8*)(&Btile[wcol + j * 16 + l15][kc]);
#pragma unroll
      for (int i = 0; i < 2; ++i)
#pragma unroll
        for (int j = 0; j < 4; ++j)
          acc[i][j] = __builtin_amdgcn_mfma_f32_16x16x32_bf16(
              af[i], bfr[j], acc[i][j], 0, 0, 0);
    }
    __syncthreads();
  }

  // epilogue: b0 = bf16(t0*(acc+bias)) via LDS transpose.
  float t0 = temp[0];
#pragma unroll
  for (int i = 0; i < 2; ++i) {
    int lrow0 = wrow + i * 16 + quad * 4;
#pragma unroll
    for (int j = 0; j < 4; ++j) {
      int gcol = wcol + j * 16 + l15;
      float bb = bias[gcol];
#pragma unroll
      for (int r = 0; r < 4; ++r)
        Atile[lrow0 + r][gcol] = f2bf(t0 * (acc[i][j][r] + bb));
    }
  }
  __syncthreads();
#pragma unroll
  for (int it = 0; it < 4; ++it) {
    int chunk = it * 256 + tid;
    int r = chunk >> 4, cc = (chunk & 15) << 3;
    int grow = row0 + r;
    if (grow < N_NODES)
      *(uint4*)(b0out + (size_t)grow * HID + cc) = *(const uint4*)(&Atile[r][cc]);
  }
}

// ---------------------------------------------------------------- layer MFMA GEMM
// R18: M=128 tile (grid 391), 4 waves each 64x64 (acc 4x4). A fragments read
// DIRECT from global (curA p=0, aggB p>0): 16B/lane contiguous, rows read
// exactly once -> no LDS A-stage, no A barrier. LDS = B panel only (34.8 KB),
// reused as the epilogue transpose buffer. B L2 restage halved vs M=64.
__global__ __launch_bounds__(256) void gemm_layer(
    const unsigned short* __restrict__ curA,   // [N,128] bf16 (in, = b_l)
    const unsigned short* __restrict__ aggB,   // [N,896] bf16
    const unsigned short* __restrict__ BT,     // wcat2T [128][1024] bf16
    const float* __restrict__ bias,
    unsigned short* __restrict__ bout,         // [N,128] bf16 (out, = b_{l+1})
    int layer)
{
  __shared__ unsigned short Btile[128][136];   // 34.8 KB (B panel / C transpose)
  const int tid  = threadIdx.x;
  const int row0 = blockIdx.x * 128;
  const int lane = tid & 63;
  const int wid  = tid >> 6;
  const int wrow = (wid & 1) * 64;
  const int wcol = (wid >> 1) * 64;
  const int l15  = lane & 15;
  const int quad = lane >> 4;

  floatx4 acc[4][4] = {};

  for (int p = 0; p < 8; ++p) {
    // B tile: 128 rows (out cols) x 128 k slice. 2048 chunks, 8/thread.
#pragma unroll
    for (int it = 0; it < 8; ++it) {
      int chunk = it * 256 + tid;
      int n = chunk >> 4, cc = (chunk & 15) << 3;
      *(uint4*)(&Btile[n][cc]) =
          *(const uint4*)(BT + (size_t)n * K_CAT + p * 128 + cc);
    }
    __syncthreads();
#pragma unroll
    for (int ks = 0; ks < 4; ++ks) {
      int kc = ks * 32 + quad * 8;
      short8 af[4], bfr[4];
#pragma unroll
      for (int i = 0; i < 4; ++i) {
        int grow = row0 + wrow + i * 16 + l15;
        short8 v = {};
        if (grow < N_NODES) {
          const unsigned short* ap = (p == 0)
              ? curA + (size_t)grow * HID + kc
              : aggB + (size_t)grow * AGG_COLS + (p - 1) * 128 + kc;
          v = *(const short8*)ap;
        }
        af[i] = v;
      }
#pragma unroll
      for (int j = 0; j < 4; ++j)
        bfr[j] = *(const short8*)(&Btile[wcol + j * 16 + l15][kc]);
#pragma unroll
      for (int i = 0; i < 4; ++i)
#pragma unroll
        for (int j = 0; j < 4; ++j)
          acc[i][j] = __builtin_amdgcn_mfma_f32_16x16x32_bf16(
              af[i], bfr[j], acc[i][j], 0, 0, 0);
    }
    __syncthreads();
  }

  // epilogue: bout = bf16((l<2?relu:id)(acc+bias)) via LDS transpose (Btile).
  const bool isLast = (layer == L_LAYERS - 1);
#pragma unroll
  for (int i = 0; i < 4; ++i) {
    int lrow0 = wrow + i * 16 + quad * 4;
#pragma unroll
    for (int j = 0; j < 4; ++j) {
      int gcol = wcol + j * 16 + l15;
      float bb = bias[gcol];
#pragma unroll
      for (int r = 0; r < 4; ++r) {
        float c = acc[i][j][r] + bb;
        if (!isLast) c = fmaxf(c, 0.f);
        Btile[lrow0 + r][gcol] = f2bf(c);
      }
    }
  }
  __syncthreads();
#pragma unroll
  for (int it = 0; it < 8; ++it) {
    int chunk = it * 256 + tid;
    int r = chunk >> 4, cc = (chunk & 15) << 3;
    int grow = row0 + r;
    if (grow < N_NODES)
      *(uint4*)(bout + (size_t)grow * HID + cc) = *(const uint4*)(&Btile[r][cc]);
  }
}

// ---------------------------------------------------------------- final linear
// h[d] = b0 + temp[1]*b1 + temp[2]*b2 + temp[3]*b3 (bf16 terms), then lin2.
__global__ __launch_bounds__(256) void final_kernel(
    const unsigned short* __restrict__ b0, const unsigned short* __restrict__ b1,
    const unsigned short* __restrict__ b2v, const unsigned short* __restrict__ b3,
    const float* __restrict__ temp,
    const float* __restrict__ w2, const float* __restrict__ b2bias,
    float* __restrict__ out)
{
  int node = blockIdx.x * 4 + (threadIdx.x >> 6);
  int lane = threadIdx.x & 63;
  if (node >= N_NODES) return;
  float t1 = temp[1], t2 = temp[2], t3 = temp[3];
  size_t base = (size_t)node * 64 + lane;      // uint index: dims 2*lane,2*lane+1
  unsigned u0 = ((const unsigned*)b0)[base];
  unsigned u1 = ((const unsigned*)b1)[base];
  unsigned u2 = ((const unsigned*)b2v)[base];
  unsigned u3 = ((const unsigned*)b3)[base];
  float hx = bf2f((unsigned short)(u0 & 0xFFFF)) +
             t1 * bf2f((unsigned short)(u1 & 0xFFFF)) +
             t2 * bf2f((unsigned short)(u2 & 0xFFFF)) +
             t3 * bf2f((unsigned short)(u3 & 0xFFFF));
  float hy = bf2f((unsigned short)(u0 >> 16)) +
             t1 * bf2f((unsigned short)(u1 >> 16)) +
             t2 * bf2f((unsigned short)(u2 >> 16)) +
             t3 * bf2f((unsigned short)(u3 >> 16));
  int d0 = lane * 2, d1 = lane * 2 + 1;
  float a0 = hx * w2[d0 * 2 + 0] + hy * w2[d1 * 2 + 0];
  float a1 = hx * w2[d0 * 2 + 1] + hy * w2[d1 * 2 + 1];
#pragma unroll
  for (int off = 32; off > 0; off >>= 1) {
    a0 += __shfl_down(a0, off);
    a1 += __shfl_down(a1, off);
  }
  if (lane == 0) {
    out[node * 2 + 0] = a0 + b2bias[0];
    out[node * 2 + 1] = a1 + b2bias[1];
  }
}

// ---------------------------------------------------------------- launcher
extern "C" void kernel_launch(void* const* d_in, const int* in_sizes, int n_in,
                              void* d_out, int out_size, void* d_ws, size_t ws_size,
                              hipStream_t stream) {
  const float* x     = (const float*)d_in[0];
  const int*   ei    = (const int*)d_in[1];
  const int*   et    = (const int*)d_in[2];
  const float* temp  = (const float*)d_in[3];
  const float* w1    = (const float*)d_in[4];
  const float* b1    = (const float*)d_in[5];
  const float* w2    = (const float*)d_in[6];
  const float* b2    = (const float*)d_in[7];
  const float* comps = (const float*)d_in[8];
  const float* bases = (const float*)d_in[9];
  const float* roots = (const float*)d_in[10];
  const float* cbias = (const float*)d_in[11];

  char* ws = (char*)d_ws;
  size_t off = 0;
  auto take = [&](size_t bytes) {
    char* p = ws + off;
    off = (off + bytes + 255) & ~(size_t)255;
    return p;
  };
  unsigned short* wcat2T = (unsigned short*)take((size_t)WCAT_ELEMS * 2);  // 0.8 MB
  unsigned short* w1T    = (unsigned short*)take((size_t)HID * IN_C * 2);  // 64 KB
  int*   cntRel  = (int*)take((size_t)NR * 4);                  // 1.4 MB
  int*   tmpOffR = (int*)take((size_t)NR * 4);                  // 1.4 MB
  int*   blockSumsR = (int*)take((size_t)SCANR_BLOCKS * 4);
  int*   drs     = (int*)take((size_t)(NR + 1) * 4);            // 1.4 MB
  int*   erank   = (int*)take((size_t)E_EDGES * 4);             // 2.4 MB
  unsigned short* esrc = (unsigned short*)take((size_t)E_EDGES * 2); // 1.2 MB
  unsigned short* bl[L_LAYERS + 1];
  for (int i = 0; i <= L_LAYERS; ++i)
    bl[i] = (unsigned short*)take((size_t)N_NODES * HID * 2);   // 4 x 12.8 MB
  unsigned short* aggB = (unsigned short*)take((size_t)N_NODES * AGG_COLS * 2); // 89.6 MB

  hipMemsetAsync(cntRel, 0, (size_t)NR * 4, stream);

  hipLaunchKernelGGL(prep_weights,
                     dim3((WCAT_ELEMS + HID * IN_C + 255) / 256), dim3(256),
                     0, stream, w1, comps, bases, roots, w1T, wcat2T);
  hipLaunchKernelGGL(hist_kernel, dim3((E_EDGES + 255) / 256), dim3(256), 0,
                     stream, ei, et, cntRel, erank);
  hipLaunchKernelGGL(scanA_kernel, dim3(SCANR_BLOCKS), dim3(256), 0, stream,
                     cntRel, tmpOffR, blockSumsR);
  hipLaunchKernelGGL(scanB_kernel, dim3(1), dim3(256), 0, stream, blockSumsR);
  hipLaunchKernelGGL(scanC_kernel, dim3(SCANR_BLOCKS), dim3(256), 0, stream,
                     tmpOffR, blockSumsR, drs);
  hipLaunchKernelGGL(place_kernel, dim3((E_EDGES + 255) / 256), dim3(256), 0,
                     stream, ei, et, drs, erank, esrc);

  const int rowBlocks64  = (N_NODES + 63) / 64;     // 782
  const int rowBlocks128 = (N_NODES + 127) / 128;   // 391
  hipLaunchKernelGGL(gemm_lin1, dim3(rowBlocks64), dim3(256), 0, stream,
                     x, w1T, b1, temp, bl[0]);

  for (int l = 0; l < L_LAYERS; ++l) {
    hipLaunchKernelGGL(agg_reg_kernel, dim3((N_NODES + 3) / 4), dim3(256),
                       0, stream, bl[l], esrc, drs, aggB);
    hipLaunchKernelGGL(gemm_layer, dim3(rowBlocks128), dim3(256), 0, stream,
                       bl[l], aggB, wcat2T + (size_t)l * 128 * K_CAT,
                       cbias + (size_t)l * HID, bl[l + 1], l);
  }

  hipLaunchKernelGGL(final_kernel, dim3((N_NODES + 3) / 4), dim3(256), 0, stream,
                     bl[0], bl[1], bl[2], bl[3], temp, w2, b2, (float*)d_out);
}